// Round 1
// baseline (1030.690 us; speedup 1.0000x reference)
//
#include <hip/hip_runtime.h>
#include <math.h>

#define F 32
#define K 16
#define EPSN 1e-8f

// Per-degree worker: block handles 256 consecutive focal nodes of one degree.
// sW: per-block LDS holding the normalized W rows for this degree
// (rows 0..15 = W_focal, rows 16.. = W_nei flat (k*DEG+j)).
template<int DEG>
__device__ __forceinline__ void process_deg(const float* __restrict__ x,
                                            const int*   __restrict__ sel,
                                            const int*   __restrict__ nei,
                                            const float* __restrict__ Wf,
                                            const float* __restrict__ Wn,
                                            float* __restrict__ out,
                                            int nd, int i0, float* sW)
{
    constexpr int NW = K * (1 + DEG);
    const int tid = threadIdx.x;

    // normalize W rows into LDS (one thread per row; NW <= 80)
    if (tid < NW) {
        const float* src = (tid < K) ? (Wf + tid * F) : (Wn + (tid - K) * F);
        float ss = 0.f;
        #pragma unroll
        for (int f = 0; f < F; ++f) { float v = src[f]; ss += v * v; }
        const float sc = 1.f / (sqrtf(ss) + EPSN);
        #pragma unroll
        for (int f = 0; f < F; ++f) sW[tid * F + f] = src[f] * sc;
    }
    __syncthreads();

    const int i = i0 + tid;
    if (i >= nd) return;

    const int node = sel[i];

    // neighbor index loads issue immediately (coalesced)
    int nn[DEG];
    #pragma unroll
    for (int j = 0; j < DEG; ++j) nn[j] = nei[i * DEG + j];

    // Write the 3 zero quadrants of the output row NOW: they depend only on
    // `node`, so the stores drain under the gather latency instead of after it.
    float4* o = (float4*)(out + (size_t)node * (4 * K));
    const float4 z = make_float4(0.f, 0.f, 0.f, 0.f);
    #pragma unroll
    for (int b = 0; b < 4; ++b) {
        if (b != DEG - 1) {
            o[b * 4 + 0] = z; o[b * 4 + 1] = z; o[b * 4 + 2] = z; o[b * 4 + 3] = z;
        }
    }

    float acc[K];

    // Double-buffered row pipeline: while computing row r, row r+1's 8
    // float4 gathers are in flight. Buffer index is compile-time after
    // the full unroll (DEG is a template constant), so buf stays in VGPRs.
    float4 buf[2][F / 4];
    {
        const float4* xr = (const float4*)(x + (size_t)node * F);
        #pragma unroll
        for (int q = 0; q < F / 4; ++q) buf[0][q] = xr[q];
    }

    #pragma unroll
    for (int r = 0; r <= DEG; ++r) {
        // issue next row's loads before consuming the current row
        if (r < DEG) {
            const float4* xr = (const float4*)(x + (size_t)nn[r] * F);
            #pragma unroll
            for (int q = 0; q < F / 4; ++q) buf[(r + 1) & 1][q] = xr[q];
        }

        const float4* rw = buf[r & 1];
        float ss = 0.f;
        #pragma unroll
        for (int q = 0; q < F / 4; ++q)
            ss += rw[q].x * rw[q].x + rw[q].y * rw[q].y
                + rw[q].z * rw[q].z + rw[q].w * rw[q].w;
        float sc = 1.f / (sqrtf(ss) + EPSN);
        if (r > 0) sc *= (1.f / (float)DEG);

        #pragma unroll
        for (int k = 0; k < K; ++k) {
            const int wrow = (r == 0) ? k : (K + k * DEG + (r - 1));
            float s = 0.f;
            #pragma unroll
            for (int q = 0; q < F / 4; ++q) {
                const float4 w = *(const float4*)&sW[wrow * F + q * 4];  // uniform broadcast
                s += w.x * rw[q].x + w.y * rw[q].y + w.z * rw[q].z + w.w * rw[q].w;
            }
            if (r == 0) acc[k] = s * sc;
            else        acc[k] += s * sc;
        }
    }

    // final 16-float band for this degree
    const int b = DEG - 1;
    o[b * 4 + 0] = make_float4(acc[0],  acc[1],  acc[2],  acc[3]);
    o[b * 4 + 1] = make_float4(acc[4],  acc[5],  acc[6],  acc[7]);
    o[b * 4 + 2] = make_float4(acc[8],  acc[9],  acc[10], acc[11]);
    o[b * 4 + 3] = make_float4(acc[12], acc[13], acc[14], acc[15]);
}

struct Args {
    const float* x;
    const int*   sel[4];
    const int*   nei[4];
    const float* Wf[4];
    const float* Wn[4];
    int nd[4];
    int bcum[4];   // cumulative block counts: after deg1, deg1+2, ...
};

// (256, 4): 4 waves/EU min -> compiler caps VGPR at 128 -> 4 blocks/CU
// (vs 132 VGPR = 2 waves/SIMD at the 128-reg occupancy cliff, m69).
__global__ __launch_bounds__(256, 4)
void fused_kernel(Args a, float* __restrict__ out)
{
    __shared__ float sW[K * 5 * F];   // max NW (deg4: 80 rows) * 32 = 10 KB
    const int bid = blockIdx.x;

    if (bid < a.bcum[0]) {
        process_deg<1>(a.x, a.sel[0], a.nei[0], a.Wf[0], a.Wn[0], out,
                       a.nd[0], bid * 256, sW);
    } else if (bid < a.bcum[1]) {
        process_deg<2>(a.x, a.sel[1], a.nei[1], a.Wf[1], a.Wn[1], out,
                       a.nd[1], (bid - a.bcum[0]) * 256, sW);
    } else if (bid < a.bcum[2]) {
        process_deg<3>(a.x, a.sel[2], a.nei[2], a.Wf[2], a.Wn[2], out,
                       a.nd[2], (bid - a.bcum[1]) * 256, sW);
    } else {
        process_deg<4>(a.x, a.sel[3], a.nei[3], a.Wf[3], a.Wn[3], out,
                       a.nd[3], (bid - a.bcum[2]) * 256, sW);
    }
}

extern "C" void kernel_launch(void* const* d_in, const int* in_sizes, int n_in,
                              void* d_out, int out_size, void* d_ws, size_t ws_size,
                              hipStream_t stream)
{
    Args a;
    a.x = (const float*)d_in[0];
    for (int d = 0; d < 4; ++d) {
        a.sel[d] = (const int*)  d_in[1 + 4 * d];
        a.nei[d] = (const int*)  d_in[2 + 4 * d];
        a.Wf[d]  = (const float*)d_in[3 + 4 * d];
        a.Wn[d]  = (const float*)d_in[4 + 4 * d];
        a.nd[d]  = in_sizes[1 + 4 * d];
    }
    int cum = 0;
    for (int d = 0; d < 4; ++d) {
        cum += (a.nd[d] + 255) / 256;
        a.bcum[d] = cum;
    }
    float* out = (float*)d_out;
    fused_kernel<<<cum, 256, 0, stream>>>(a, out);
}